// Round 5
// baseline (178.467 us; speedup 1.0000x reference)
//
#include <hip/hip_runtime.h>
#include <math.h>

#define EPS 1e-6f

typedef _Float16 half8 __attribute__((ext_vector_type(8)));
typedef float f32x16 __attribute__((ext_vector_type(16)));

// ---------------- Kernel 1: h = LayerNorm(relu(x @ Wh + bh)) + hsum ---------
// 64 blocks x 512 threads; thread t owns column t
__global__ __launch_bounds__(512) void k_fch_ln(
    const float* __restrict__ x, const float* __restrict__ Wh,
    const float* __restrict__ bh, const float* __restrict__ ls,
    const float* __restrict__ lb, float* __restrict__ hout,
    float* __restrict__ hsum) {
    const int b = blockIdx.x;
    const int t = threadIdx.x;
    __shared__ float xs[512];
    __shared__ float wred[3][8];

    xs[t] = x[b * 512 + t];
    __syncthreads();

    float acc = bh[t];
#pragma unroll 8
    for (int k = 0; k < 512; ++k)
        acc = fmaf(xs[k], Wh[k * 512 + t], acc);
    acc = fmaxf(acc, 0.0f);

    float s = acc, ss = acc * acc;
#pragma unroll
    for (int m = 1; m < 64; m <<= 1) {
        s  += __shfl_xor(s, m);
        ss += __shfl_xor(ss, m);
    }
    const int wv = t >> 6;
    if ((t & 63) == 0) { wred[0][wv] = s; wred[1][wv] = ss; }
    __syncthreads();
    s = 0.f; ss = 0.f;
#pragma unroll
    for (int i = 0; i < 8; ++i) { s += wred[0][i]; ss += wred[1][i]; }

    float mean = s * (1.0f / 512.0f);
    float var  = ss * (1.0f / 512.0f) - mean * mean;
    float rstd = rsqrtf(var + EPS);
    float hval = (acc - mean) * rstd * ls[t] + lb[t];
    hout[b * 512 + t] = hval;

    // row sum of h (Vsum)
    float sv = hval;
#pragma unroll
    for (int m = 1; m < 64; m <<= 1) sv += __shfl_xor(sv, m);
    __syncthreads();
    if ((t & 63) == 0) wred[2][wv] = sv;
    __syncthreads();
    if (t == 0) {
        float tot = 0.f;
#pragma unroll
        for (int i = 0; i < 8; ++i) tot += wred[2][i];
        hsum[b] = tot;
    }
}

// ---------------- Kernel 2: xz{1,2} = x @ Wz{1,2}[:512,:] -------------------
// grid (16, 16): bx = half*8 + colchunk(512 cols); by = ksplit(16) of 32 k.
// All 64 batch rows per block -> W read ONCE from HBM. Partials via atomicAdd.
__global__ __launch_bounds__(256, 1) void k_xz(
    const float* __restrict__ x, const float* __restrict__ Wz1,
    const float* __restrict__ Wz2, float* __restrict__ xz1,
    float* __restrict__ xz2) {
    const int bx   = blockIdx.x;
    const int half = bx >> 3;
    const int cb   = (bx & 7) * 512;
    const int k0   = blockIdx.y * 32;
    const int t    = threadIdx.x;

    __shared__ float xs[64 * 32];
#pragma unroll
    for (int j = 0; j < 8; ++j) {
        const int e = j * 256 + t;
        const int row = e >> 5, kk = e & 31;
        xs[e] = x[row * 512 + k0 + kk];
    }
    __syncthreads();

    const float* __restrict__ W   = half ? Wz2 : Wz1;
    float* __restrict__       out = half ? xz2 : xz1;
    const int c = cb + 2 * t;

    float2 acc[64];
#pragma unroll
    for (int r_ = 0; r_ < 64; ++r_) acc[r_] = make_float2(0.f, 0.f);

#pragma unroll 1
    for (int g4 = 0; g4 < 8; ++g4) {
        float2 w0 = *(const float2*)(W + (size_t)(k0 + g4 * 4 + 0) * 4096 + c);
        float2 w1 = *(const float2*)(W + (size_t)(k0 + g4 * 4 + 1) * 4096 + c);
        float2 w2 = *(const float2*)(W + (size_t)(k0 + g4 * 4 + 2) * 4096 + c);
        float2 w3 = *(const float2*)(W + (size_t)(k0 + g4 * 4 + 3) * 4096 + c);
#pragma unroll
        for (int r_ = 0; r_ < 64; ++r_) {
            float4 xv = *(const float4*)(xs + r_ * 32 + g4 * 4);
            acc[r_].x = fmaf(xv.x, w0.x, acc[r_].x);
            acc[r_].y = fmaf(xv.x, w0.y, acc[r_].y);
            acc[r_].x = fmaf(xv.y, w1.x, acc[r_].x);
            acc[r_].y = fmaf(xv.y, w1.y, acc[r_].y);
            acc[r_].x = fmaf(xv.z, w2.x, acc[r_].x);
            acc[r_].y = fmaf(xv.z, w2.y, acc[r_].y);
            acc[r_].x = fmaf(xv.w, w3.x, acc[r_].x);
            acc[r_].y = fmaf(xv.w, w3.y, acc[r_].y);
        }
    }
#pragma unroll
    for (int r_ = 0; r_ < 64; ++r_) {
        atomicAdd(out + r_ * 4096 + c,     acc[r_].x);
        atomicAdd(out + r_ * 4096 + c + 1, acc[r_].y);
    }
}

// ---------------- Kernel 2.5: per-row prep: z f16, stats, A-prescale, Bg ----
// 1024 blocks (one per row r); writes z1h[r][d][h8], z2h (A-prescaled), Bg.
__global__ __launch_bounds__(256, 4) void k_prep(
    const float* __restrict__ xz1, const float* __restrict__ xz2,
    const float* __restrict__ Wz1, const float* __restrict__ Wz2,
    _Float16* __restrict__ z1h, _Float16* __restrict__ z2h,
    float* __restrict__ Bg) {
    const int r  = blockIdx.x;
    const int br = r >> 4, a = r & 15;
    const int t  = threadIdx.x;
    const int l  = t & 63, wv = t >> 6;

    __shared__ float red[44 * 4];
    __shared__ float Ssum[44];

    const float* __restrict__ x1  = xz1 + br * 4096;
    const float* __restrict__ x2  = xz2 + br * 4096;
    const float* __restrict__ w1r = Wz1 + (512 + a) * 4096;
    const float* __restrict__ w2r = Wz2 + (512 + a) * 4096;

    float pm[8], pg[36];
#pragma unroll
    for (int i = 0; i < 8; ++i) pm[i] = 0.f;
#pragma unroll
    for (int i = 0; i < 36; ++i) pg[i] = 0.f;

    half8 h2keep[2];
#pragma unroll
    for (int p = 0; p < 2; ++p) {
        const int d = t + p * 256;
        half8 h1, h2;
#pragma unroll
        for (int h = 0; h < 8; ++h) {
            float z1v = x1[h * 512 + d] + w1r[h * 512 + d];
            float z2v = x2[h * 512 + d] + w2r[h * 512 + d];
            h1[h] = (_Float16)z1v;
            h2[h] = (_Float16)z2v;
        }
        *(half8*)(z1h + ((size_t)r * 512 + d) * 8) = h1;
        h2keep[p] = h2;
        float zr[8];
#pragma unroll
        for (int h = 0; h < 8; ++h) zr[h] = (float)h1[h];
#pragma unroll
        for (int h = 0; h < 8; ++h) pm[h] += zr[h];
        int id = 0;
#pragma unroll
        for (int h = 0; h < 8; ++h)
#pragma unroll
            for (int h2_ = h; h2_ < 8; ++h2_) { pg[id] += zr[h] * zr[h2_]; ++id; }
    }

#pragma unroll
    for (int m = 1; m < 64; m <<= 1) {
#pragma unroll
        for (int i = 0; i < 8; ++i)  pm[i] += __shfl_xor(pm[i], m);
#pragma unroll
        for (int i = 0; i < 36; ++i) pg[i] += __shfl_xor(pg[i], m);
    }
    if (l == 0) {
#pragma unroll
        for (int i = 0; i < 8; ++i)  red[i * 4 + wv]       = pm[i];
#pragma unroll
        for (int i = 0; i < 36; ++i) red[(8 + i) * 4 + wv] = pg[i];
    }
    __syncthreads();
    if (t < 44) Ssum[t] = red[t * 4 + 0] + red[t * 4 + 1] + red[t * 4 + 2] + red[t * 4 + 3];
    __syncthreads();

    const float C2LE = 2.8853900817779268f;  // 2*log2(e)
#pragma unroll
    for (int p = 0; p < 2; ++p) {
        const int g = t + p * 256;
        float zv[8];
#pragma unroll
        for (int h = 0; h < 8; ++h) zv[h] = (float)h2keep[p][h];
        float mean = 0.f;
#pragma unroll
        for (int h = 0; h < 8; ++h) mean = fmaf(zv[h], Ssum[h], mean);
        mean *= (1.0f / 512.0f);
        float e2 = 0.f;
        int id = 0;
#pragma unroll
        for (int h = 0; h < 8; ++h)
#pragma unroll
            for (int h2_ = h; h2_ < 8; ++h2_) {
                float p2 = zv[h] * zv[h2_] * Ssum[8 + id];
                e2 += (h2_ == h) ? p2 : 2.0f * p2;
                ++id;
            }
        e2 *= (1.0f / 512.0f);
        float var  = e2 - mean * mean;
        float sd   = sqrtf(fmaxf(var, 0.f));
        float rstd = 1.0f / (sd + EPS);
        float A = rstd * C2LE;
        Bg[r * 512 + g] = -mean * rstd * C2LE;
        half8 hs;
#pragma unroll
        for (int h = 0; h < 8; ++h) hs[h] = (_Float16)(zv[h] * A);
        *(half8*)(z2h + ((size_t)r * 512 + g) * 8) = hs;
    }
}

// ---------------- Kernel 3: MFMA bilinear + tanh + dot (compute only) -------
// 2048 blocks: blockIdx.x = r*2 + gh; block handles local g in [0,256)
__global__ __launch_bounds__(256, 4) void k_main(
    const _Float16* __restrict__ z1h, const _Float16* __restrict__ z2h,
    const float* __restrict__ Bg, const float* __restrict__ hbuf,
    const float* __restrict__ hsum, float* __restrict__ yout,
    float* __restrict__ qout) {
    const int bx = blockIdx.x;
    const int r  = bx >> 1, gh = bx & 1;
    const int br = r >> 4;
    const int t  = threadIdx.x;
    const int l  = t & 63, wv = t >> 6;
    const int hi = l >> 5, l31 = l & 31;

    __shared__ __align__(16) _Float16 z1t[513 * 8];   // [d][h], row 512 = zeros
    __shared__ __align__(16) _Float16 z2t[257 * 8];   // [g_local][h] (A-scaled)
    __shared__ float Bs[256];
    __shared__ float vs[512];
    __shared__ float ys[256];
    __shared__ float wq[4];

    // ---- phase 1: pure staging (f16 copies) ----
#pragma unroll
    for (int p = 0; p < 2; ++p) {
        const int d = t + p * 256;
        *(half8*)(z1t + d * 8) = *(const half8*)(z1h + ((size_t)r * 512 + d) * 8);
    }
    *(half8*)(z2t + t * 8) = *(const half8*)(z2h + ((size_t)r * 512 + gh * 256 + t) * 8);
    Bs[t] = Bg[r * 512 + gh * 256 + t];
    vs[t]       = hbuf[br * 512 + t];
    vs[t + 256] = hbuf[br * 512 + t + 256];
    if (t == 0) {
        half8 hz = {};
        *(half8*)(z1t + 512 * 8) = hz;
        *(half8*)(z2t + 256 * 8) = hz;
    }
    __syncthreads();

    const float Vsum = hsum[br];

    // ---- phase 2: MFMA tiles + finish (3 VALU + 2 trans per element) ----
    const f32x16 CZ = {0.f, 0.f, 0.f, 0.f, 0.f, 0.f, 0.f, 0.f,
                       0.f, 0.f, 0.f, 0.f, 0.f, 0.f, 0.f, 0.f};
    float qacc = 0.f;
#pragma unroll 1
    for (int mi = 0; mi < 2; ++mi) {
        const int m0 = (wv * 2 + mi) * 32;              // local g tile base
        const int arow = hi ? 256 : (m0 + l31);
        const half8 Af = *(const half8*)(z2t + arow * 8);
        float bv[16];
#pragma unroll
        for (int rg = 0; rg < 16; ++rg)
            bv[rg] = Bs[m0 + (rg & 3) + 8 * (rg >> 2) + 4 * hi];
        float yac[16];
#pragma unroll
        for (int i = 0; i < 16; ++i) yac[i] = 0.f;

#pragma unroll 1
        for (int nt = 0; nt < 16; ++nt) {
            const int n0 = nt * 32;
            const int brow = hi ? 512 : (n0 + l31);
            const half8 Bf = *(const half8*)(z1t + brow * 8);
            const float vv = vs[n0 + l31];
            f32x16 D = __builtin_amdgcn_mfma_f32_32x32x16_f16(Af, Bf, CZ, 0, 0, 0);
#pragma unroll
            for (int i = 0; i < 16; ++i) {
                float wn = D[i] + bv[i];                 // pre-scaled: 2x*log2e
                float e  = __builtin_amdgcn_exp2f(wn);   // e^{2x}
                float r1 = __builtin_amdgcn_rcpf(e + 1.0f);
                yac[i] = fmaf(vv, r1, yac[i]);           // sum v/(e^{2x}+1)
            }
        }
#pragma unroll
        for (int i = 0; i < 16; ++i) {
#pragma unroll
            for (int m = 1; m <= 16; m <<= 1) yac[i] += __shfl_xor(yac[i], m);
        }
        if (l31 == 0) {
#pragma unroll
            for (int i = 0; i < 16; ++i) {
                const int g = m0 + (i & 3) + 8 * (i >> 2) + 4 * hi;
                float yv = fmaf(-2.0f, yac[i], Vsum);    // Vsum - 2*sum
                ys[g] = yv;
                qacc = fmaf(yv, yv, qacc);
            }
        }
    }
    qacc += __shfl_xor(qacc, 32);
    if (l == 0) wq[wv] = qacc;
    __syncthreads();
    if (t == 0) atomicAdd(qout + r, (wq[0] + wq[1] + wq[2] + wq[3]) * (1.0f / 512.0f));
    yout[r * 512 + gh * 256 + t] = ys[t];
}

// ---------------------------------------------------------------------------
extern "C" void kernel_launch(void* const* d_in, const int* in_sizes, int n_in,
                              void* d_out, int out_size, void* d_ws, size_t ws_size,
                              hipStream_t stream) {
    const float* x   = (const float*)d_in[0];   // (64, 512)
    const float* Wh  = (const float*)d_in[1];   // (512, 512)
    const float* bh  = (const float*)d_in[2];   // (512,)
    const float* ls  = (const float*)d_in[3];   // (512,)
    const float* lb  = (const float*)d_in[4];   // (512,)
    const float* Wz1 = (const float*)d_in[5];   // (528, 4096)
    const float* Wz2 = (const float*)d_in[6];   // (528, 4096)

    float* out  = (float*)d_out;
    float* hout = out;                 // 64*512
    float* qout = out + 32768;         // 64*16
    float* yout = out + 33792;         // 1024*512

    // workspace layout (bytes)
    char* ws = (char*)d_ws;
    float*     xz1  = (float*)(ws);                        // 1 MB
    float*     xz2  = (float*)(ws + (1u << 20));           // 1 MB
    float*     Bg   = (float*)(ws + (2u << 20));           // 2 MB (1024*512 f32)
    float*     hsum = (float*)(ws + (4u << 20));           // 256 B
    _Float16*  z1h  = (_Float16*)(ws + (4u << 20) + 4096); // 8.4 MB
    _Float16*  z2h  = z1h + (size_t)1024 * 512 * 8;        // 8.4 MB

    hipMemsetAsync(xz1, 0, (size_t)2 * 64 * 4096 * sizeof(float), stream);
    hipMemsetAsync(qout, 0, 64 * 16 * sizeof(float), stream);

    k_fch_ln<<<64, 512, 0, stream>>>(x, Wh, bh, ls, lb, hout, hsum);
    k_xz<<<dim3(16, 16), 256, 0, stream>>>(x, Wz1, Wz2, xz1, xz2);
    k_prep<<<1024, 256, 0, stream>>>(xz1, xz2, Wz1, Wz2, z1h, z2h, Bg);
    k_main<<<2048, 256, 0, stream>>>(z1h, z2h, Bg, hout, hsum, yout, qout);
}

// Round 6
// 124.856 us; speedup vs baseline: 1.4294x; 1.4294x over previous
//
#include <hip/hip_runtime.h>
#include <math.h>

#define EPS 1e-6f

typedef _Float16 half8 __attribute__((ext_vector_type(8)));
typedef float f32x16 __attribute__((ext_vector_type(16)));

// ---------------- Kernel 1: h = LayerNorm(relu(x @ Wh + bh)) + hsum + xh ----
// 64 blocks x 512 threads; thread t owns column t
__global__ __launch_bounds__(512) void k_fch_ln(
    const float* __restrict__ x, const float* __restrict__ Wh,
    const float* __restrict__ bh, const float* __restrict__ ls,
    const float* __restrict__ lb, float* __restrict__ hout,
    float* __restrict__ hsum, _Float16* __restrict__ xh) {
    const int b = blockIdx.x;
    const int t = threadIdx.x;
    __shared__ float xs[512];
    __shared__ float wred[3][8];

    float xv = x[b * 512 + t];
    xs[t] = xv;
    xh[b * 512 + t] = (_Float16)xv;      // f16 copy of x for the MFMA GEMM
    __syncthreads();

    float acc = bh[t];
#pragma unroll 8
    for (int k = 0; k < 512; ++k)
        acc = fmaf(xs[k], Wh[k * 512 + t], acc);
    acc = fmaxf(acc, 0.0f);

    float s = acc, ss = acc * acc;
#pragma unroll
    for (int m = 1; m < 64; m <<= 1) {
        s  += __shfl_xor(s, m);
        ss += __shfl_xor(ss, m);
    }
    const int wv = t >> 6;
    if ((t & 63) == 0) { wred[0][wv] = s; wred[1][wv] = ss; }
    __syncthreads();
    s = 0.f; ss = 0.f;
#pragma unroll
    for (int i = 0; i < 8; ++i) { s += wred[0][i]; ss += wred[1][i]; }

    float mean = s * (1.0f / 512.0f);
    float var  = ss * (1.0f / 512.0f) - mean * mean;
    float rstd = rsqrtf(var + EPS);
    float hval = (acc - mean) * rstd * ls[t] + lb[t];
    hout[b * 512 + t] = hval;

    // row sum of h (Vsum)
    float sv = hval;
#pragma unroll
    for (int m = 1; m < 64; m <<= 1) sv += __shfl_xor(sv, m);
    __syncthreads();
    if ((t & 63) == 0) wred[2][wv] = sv;
    __syncthreads();
    if (t == 0) {
        float tot = 0.f;
#pragma unroll
        for (int i = 0; i < 8; ++i) tot += wred[2][i];
        hsum[b] = tot;
    }
}

// ---------------- Kernel 2: xz{1,2} = xh @ Wz{1,2}[:512,:] via MFMA ---------
// 64 blocks x 256 threads (4 waves). Block: W-half (bx>>5), 128-col strip.
// Wave w: cols n0 = strip + 32*w, all 64 rows (2 MFMA tiles), full K=512.
// W read exactly once from HBM; no atomics.
__global__ __launch_bounds__(256) void k_xz(
    const _Float16* __restrict__ xh, const float* __restrict__ Wz1,
    const float* __restrict__ Wz2, float* __restrict__ xz1,
    float* __restrict__ xz2) {
    const int bx  = blockIdx.x;
    const int half = bx >> 5;
    const int bn  = (bx & 31) * 128;
    const int t   = threadIdx.x;
    const int l   = t & 63, w = t >> 6;
    const int hi  = l >> 5, l31 = l & 31;

    const float* __restrict__ W   = half ? Wz2 : Wz1;
    float* __restrict__       out = half ? xz2 : xz1;
    const int n0 = bn + 32 * w;

    const f32x16 CZ = {0.f, 0.f, 0.f, 0.f, 0.f, 0.f, 0.f, 0.f,
                       0.f, 0.f, 0.f, 0.f, 0.f, 0.f, 0.f, 0.f};
    f32x16 acc0 = CZ;   // rows 0-31
    f32x16 acc1 = CZ;   // rows 32-63

    const _Float16* __restrict__ a0p = xh + l31 * 512 + 8 * hi;
    const _Float16* __restrict__ a1p = xh + (32 + l31) * 512 + 8 * hi;
    const float* __restrict__    wp  = W + (size_t)(8 * hi) * 4096 + n0 + l31;

#pragma unroll 4
    for (int k0 = 0; k0 < 512; k0 += 16) {
        half8 a0 = *(const half8*)(a0p + k0);
        half8 a1 = *(const half8*)(a1p + k0);
        const float* wk = wp + (size_t)k0 * 4096;
        half8 bf;
#pragma unroll
        for (int j = 0; j < 8; ++j)
            bf[j] = (_Float16)wk[(size_t)j * 4096];
        acc0 = __builtin_amdgcn_mfma_f32_32x32x16_f16(a0, bf, acc0, 0, 0, 0);
        acc1 = __builtin_amdgcn_mfma_f32_32x32x16_f16(a1, bf, acc1, 0, 0, 0);
    }
#pragma unroll
    for (int i = 0; i < 16; ++i) {
        const int m = (i & 3) + 8 * (i >> 2) + 4 * hi;
        out[(size_t)m * 4096 + n0 + l31]        = acc0[i];
        out[(size_t)(m + 32) * 4096 + n0 + l31] = acc1[i];
    }
}

// ---------------- Kernel 2.5: per-row prep: z f16, stats, A-prescale, Bg ----
// 1024 blocks (one per row r); writes z1h[r][d][h8], z2h (A-prescaled), Bg.
__global__ __launch_bounds__(256, 4) void k_prep(
    const float* __restrict__ xz1, const float* __restrict__ xz2,
    const float* __restrict__ Wz1, const float* __restrict__ Wz2,
    _Float16* __restrict__ z1h, _Float16* __restrict__ z2h,
    float* __restrict__ Bg) {
    const int r  = blockIdx.x;
    const int br = r >> 4, a = r & 15;
    const int t  = threadIdx.x;
    const int l  = t & 63, wv = t >> 6;

    __shared__ float red[44 * 4];
    __shared__ float Ssum[44];

    const float* __restrict__ x1  = xz1 + br * 4096;
    const float* __restrict__ x2  = xz2 + br * 4096;
    const float* __restrict__ w1r = Wz1 + (512 + a) * 4096;
    const float* __restrict__ w2r = Wz2 + (512 + a) * 4096;

    float pm[8], pg[36];
#pragma unroll
    for (int i = 0; i < 8; ++i) pm[i] = 0.f;
#pragma unroll
    for (int i = 0; i < 36; ++i) pg[i] = 0.f;

    half8 h2keep[2];
#pragma unroll
    for (int p = 0; p < 2; ++p) {
        const int d = t + p * 256;
        half8 h1, h2;
#pragma unroll
        for (int h = 0; h < 8; ++h) {
            float z1v = x1[h * 512 + d] + w1r[h * 512 + d];
            float z2v = x2[h * 512 + d] + w2r[h * 512 + d];
            h1[h] = (_Float16)z1v;
            h2[h] = (_Float16)z2v;
        }
        *(half8*)(z1h + ((size_t)r * 512 + d) * 8) = h1;
        h2keep[p] = h2;
        float zr[8];
#pragma unroll
        for (int h = 0; h < 8; ++h) zr[h] = (float)h1[h];
#pragma unroll
        for (int h = 0; h < 8; ++h) pm[h] += zr[h];
        int id = 0;
#pragma unroll
        for (int h = 0; h < 8; ++h)
#pragma unroll
            for (int h2_ = h; h2_ < 8; ++h2_) { pg[id] += zr[h] * zr[h2_]; ++id; }
    }

#pragma unroll
    for (int m = 1; m < 64; m <<= 1) {
#pragma unroll
        for (int i = 0; i < 8; ++i)  pm[i] += __shfl_xor(pm[i], m);
#pragma unroll
        for (int i = 0; i < 36; ++i) pg[i] += __shfl_xor(pg[i], m);
    }
    if (l == 0) {
#pragma unroll
        for (int i = 0; i < 8; ++i)  red[i * 4 + wv]       = pm[i];
#pragma unroll
        for (int i = 0; i < 36; ++i) red[(8 + i) * 4 + wv] = pg[i];
    }
    __syncthreads();
    if (t < 44) Ssum[t] = red[t * 4 + 0] + red[t * 4 + 1] + red[t * 4 + 2] + red[t * 4 + 3];
    __syncthreads();

    const float C2LE = 2.8853900817779268f;  // 2*log2(e)
#pragma unroll
    for (int p = 0; p < 2; ++p) {
        const int g = t + p * 256;
        float zv[8];
#pragma unroll
        for (int h = 0; h < 8; ++h) zv[h] = (float)h2keep[p][h];
        float mean = 0.f;
#pragma unroll
        for (int h = 0; h < 8; ++h) mean = fmaf(zv[h], Ssum[h], mean);
        mean *= (1.0f / 512.0f);
        float e2 = 0.f;
        int id = 0;
#pragma unroll
        for (int h = 0; h < 8; ++h)
#pragma unroll
            for (int h2_ = h; h2_ < 8; ++h2_) {
                float p2 = zv[h] * zv[h2_] * Ssum[8 + id];
                e2 += (h2_ == h) ? p2 : 2.0f * p2;
                ++id;
            }
        e2 *= (1.0f / 512.0f);
        float var  = e2 - mean * mean;
        float sd   = sqrtf(fmaxf(var, 0.f));
        float rstd = 1.0f / (sd + EPS);
        float A = rstd * C2LE;
        Bg[r * 512 + g] = -mean * rstd * C2LE;
        half8 hs;
#pragma unroll
        for (int h = 0; h < 8; ++h) hs[h] = (_Float16)(zv[h] * A);
        *(half8*)(z2h + ((size_t)r * 512 + g) * 8) = hs;
    }
}

// ---------------- Kernel 3: MFMA bilinear + tanh + dot (compute only) -------
// 2048 blocks: blockIdx.x = r*2 + gh; block handles local g in [0,256)
__global__ __launch_bounds__(256, 4) void k_main(
    const _Float16* __restrict__ z1h, const _Float16* __restrict__ z2h,
    const float* __restrict__ Bg, const float* __restrict__ hbuf,
    const float* __restrict__ hsum, float* __restrict__ yout,
    float* __restrict__ qout) {
    const int bx = blockIdx.x;
    const int r  = bx >> 1, gh = bx & 1;
    const int br = r >> 4;
    const int t  = threadIdx.x;
    const int l  = t & 63, wv = t >> 6;
    const int hi = l >> 5, l31 = l & 31;

    __shared__ __align__(16) _Float16 z1t[513 * 8];   // [d][h], row 512 = zeros
    __shared__ __align__(16) _Float16 z2t[257 * 8];   // [g_local][h] (A-scaled)
    __shared__ float Bs[256];
    __shared__ float vs[512];
    __shared__ float ys[256];
    __shared__ float wq[4];

    // ---- phase 1: pure staging (f16 copies) ----
#pragma unroll
    for (int p = 0; p < 2; ++p) {
        const int d = t + p * 256;
        *(half8*)(z1t + d * 8) = *(const half8*)(z1h + ((size_t)r * 512 + d) * 8);
    }
    *(half8*)(z2t + t * 8) = *(const half8*)(z2h + ((size_t)r * 512 + gh * 256 + t) * 8);
    Bs[t] = Bg[r * 512 + gh * 256 + t];
    vs[t]       = hbuf[br * 512 + t];
    vs[t + 256] = hbuf[br * 512 + t + 256];
    if (t == 0) {
        half8 hz = {};
        *(half8*)(z1t + 512 * 8) = hz;
        *(half8*)(z2t + 256 * 8) = hz;
    }
    __syncthreads();

    const float Vsum = hsum[br];

    // ---- phase 2: MFMA tiles + finish (3 VALU + 2 trans per element) ----
    const f32x16 CZ = {0.f, 0.f, 0.f, 0.f, 0.f, 0.f, 0.f, 0.f,
                       0.f, 0.f, 0.f, 0.f, 0.f, 0.f, 0.f, 0.f};
    float qacc = 0.f;
#pragma unroll 1
    for (int mi = 0; mi < 2; ++mi) {
        const int m0 = (wv * 2 + mi) * 32;              // local g tile base
        const int arow = hi ? 256 : (m0 + l31);
        const half8 Af = *(const half8*)(z2t + arow * 8);
        float bv[16];
#pragma unroll
        for (int rg = 0; rg < 16; ++rg)
            bv[rg] = Bs[m0 + (rg & 3) + 8 * (rg >> 2) + 4 * hi];
        float yac[16];
#pragma unroll
        for (int i = 0; i < 16; ++i) yac[i] = 0.f;

#pragma unroll 1
        for (int nt = 0; nt < 16; ++nt) {
            const int n0 = nt * 32;
            const int brow = hi ? 512 : (n0 + l31);
            const half8 Bf = *(const half8*)(z1t + brow * 8);
            const float vv = vs[n0 + l31];
            f32x16 D = __builtin_amdgcn_mfma_f32_32x32x16_f16(Af, Bf, CZ, 0, 0, 0);
#pragma unroll
            for (int i = 0; i < 16; ++i) {
                float wn = D[i] + bv[i];                 // pre-scaled: 2x*log2e
                float e  = __builtin_amdgcn_exp2f(wn);   // e^{2x}
                float r1 = __builtin_amdgcn_rcpf(e + 1.0f);
                yac[i] = fmaf(vv, r1, yac[i]);           // sum v/(e^{2x}+1)
            }
        }
#pragma unroll
        for (int i = 0; i < 16; ++i) {
#pragma unroll
            for (int m = 1; m <= 16; m <<= 1) yac[i] += __shfl_xor(yac[i], m);
        }
        if (l31 == 0) {
#pragma unroll
            for (int i = 0; i < 16; ++i) {
                const int g = m0 + (i & 3) + 8 * (i >> 2) + 4 * hi;
                float yv = fmaf(-2.0f, yac[i], Vsum);    // Vsum - 2*sum
                ys[g] = yv;
                qacc = fmaf(yv, yv, qacc);
            }
        }
    }
    qacc += __shfl_xor(qacc, 32);
    if (l == 0) wq[wv] = qacc;
    __syncthreads();
    if (t == 0) atomicAdd(qout + r, (wq[0] + wq[1] + wq[2] + wq[3]) * (1.0f / 512.0f));
    yout[r * 512 + gh * 256 + t] = ys[t];
}

// ---------------------------------------------------------------------------
extern "C" void kernel_launch(void* const* d_in, const int* in_sizes, int n_in,
                              void* d_out, int out_size, void* d_ws, size_t ws_size,
                              hipStream_t stream) {
    const float* x   = (const float*)d_in[0];   // (64, 512)
    const float* Wh  = (const float*)d_in[1];   // (512, 512)
    const float* bh  = (const float*)d_in[2];   // (512,)
    const float* ls  = (const float*)d_in[3];   // (512,)
    const float* lb  = (const float*)d_in[4];   // (512,)
    const float* Wz1 = (const float*)d_in[5];   // (528, 4096)
    const float* Wz2 = (const float*)d_in[6];   // (528, 4096)

    float* out  = (float*)d_out;
    float* hout = out;                 // 64*512
    float* qout = out + 32768;         // 64*16
    float* yout = out + 33792;         // 1024*512

    // workspace layout (bytes)
    char* ws = (char*)d_ws;
    float*     xz1  = (float*)(ws);                        // 1 MB
    float*     xz2  = (float*)(ws + (1u << 20));           // 1 MB
    float*     Bg   = (float*)(ws + (2u << 20));           // 2 MB (1024*512 f32)
    float*     hsum = (float*)(ws + (4u << 20));           // 256 B
    _Float16*  xh   = (_Float16*)(ws + (4u << 20) + 1024); // 64 KB
    _Float16*  z1h  = (_Float16*)(ws + (4u << 20) + 131072); // 8.4 MB
    _Float16*  z2h  = z1h + (size_t)1024 * 512 * 8;          // 8.4 MB

    hipMemsetAsync(qout, 0, 64 * 16 * sizeof(float), stream);

    k_fch_ln<<<64, 512, 0, stream>>>(x, Wh, bh, ls, lb, hout, hsum, xh);
    k_xz<<<64, 256, 0, stream>>>(xh, Wz1, Wz2, xz1, xz2);
    k_prep<<<1024, 256, 0, stream>>>(xz1, xz2, Wz1, Wz2, z1h, z2h, Bg);
    k_main<<<2048, 256, 0, stream>>>(z1h, z2h, Bg, hout, hsum, yout, qout);
}

// Round 7
// 98.709 us; speedup vs baseline: 1.8080x; 1.2649x over previous
//
#include <hip/hip_runtime.h>
#include <math.h>

#define EPS 1e-6f

typedef _Float16 half8 __attribute__((ext_vector_type(8)));
typedef float f32x16 __attribute__((ext_vector_type(16)));

// ---------------- Kernel 0: xh = (f16)x ------------------------------------
__global__ __launch_bounds__(256) void k_xh(
    const float* __restrict__ x, _Float16* __restrict__ xh) {
    const int i = (blockIdx.x * 256 + threadIdx.x) * 8;
    float4 a = *(const float4*)(x + i);
    float4 b = *(const float4*)(x + i + 4);
    half8 o;
    o[0] = (_Float16)a.x; o[1] = (_Float16)a.y; o[2] = (_Float16)a.z; o[3] = (_Float16)a.w;
    o[4] = (_Float16)b.x; o[5] = (_Float16)b.y; o[6] = (_Float16)b.z; o[7] = (_Float16)b.w;
    *(half8*)(xh + i) = o;
}

// ---------------- Kernel 1: fused GEMM [hpre|xz1|xz2] = xh @ [Wh|Wz1|Wz2] ---
// grid (68, 2): x = col strip of 128; y = K-half of 256. 256 thr = 4 waves.
// Wave w: cols strip+32w, all 64 rows (2 MFMA tiles). 2-addend atomicAdd.
__global__ __launch_bounds__(256) void k_gemm(
    const _Float16* __restrict__ xh, const float* __restrict__ Wh,
    const float* __restrict__ Wz1, const float* __restrict__ Wz2,
    float* __restrict__ hpre, float* __restrict__ xz1,
    float* __restrict__ xz2) {
    const int s  = blockIdx.x;
    const int k0 = blockIdx.y * 256;
    const int t  = threadIdx.x;
    const int l  = t & 63, w = t >> 6;
    const int hi = l >> 5, l31 = l & 31;
    const int cbase = s * 128;

    const float* __restrict__ W;
    float* __restrict__ out;
    int ncols, ocol;
    if (s < 4)       { W = Wh;  out = hpre; ncols = 512;  ocol = cbase; }
    else if (s < 36) { W = Wz1; out = xz1;  ncols = 4096; ocol = cbase - 512; }
    else             { W = Wz2; out = xz2;  ncols = 4096; ocol = cbase - 4608; }

    const int col = ocol + 32 * w + l31;

    const f32x16 CZ = {0.f, 0.f, 0.f, 0.f, 0.f, 0.f, 0.f, 0.f,
                       0.f, 0.f, 0.f, 0.f, 0.f, 0.f, 0.f, 0.f};
    f32x16 acc0 = CZ;   // rows 0-31
    f32x16 acc1 = CZ;   // rows 32-63

    const _Float16* __restrict__ a0p = xh + l31 * 512 + 8 * hi + k0;
    const _Float16* __restrict__ a1p = a0p + 32 * 512;
    const float* __restrict__    wp  = W + (size_t)(k0 + 8 * hi) * ncols + col;

#pragma unroll 2
    for (int kk = 0; kk < 256; kk += 16) {
        half8 a0 = *(const half8*)(a0p + kk);
        half8 a1 = *(const half8*)(a1p + kk);
        const float* wk = wp + (size_t)kk * ncols;
        half8 bf;
#pragma unroll
        for (int j = 0; j < 8; ++j)
            bf[j] = (_Float16)wk[(size_t)j * ncols];
        acc0 = __builtin_amdgcn_mfma_f32_32x32x16_f16(a0, bf, acc0, 0, 0, 0);
        acc1 = __builtin_amdgcn_mfma_f32_32x32x16_f16(a1, bf, acc1, 0, 0, 0);
    }
#pragma unroll
    for (int i = 0; i < 16; ++i) {
        const int m = (i & 3) + 8 * (i >> 2) + 4 * hi;
        atomicAdd(out + (size_t)m * ncols + col,        acc0[i]);
        atomicAdd(out + (size_t)(m + 32) * ncols + col, acc1[i]);
    }
}

// ---------------- Kernel 2: fused LN (blocks 0-63) + prep (blocks 64-1087) --
__global__ __launch_bounds__(256) void k_mid(
    const float* __restrict__ hpre, const float* __restrict__ bh,
    const float* __restrict__ ls, const float* __restrict__ lb,
    const float* __restrict__ xz1, const float* __restrict__ xz2,
    const float* __restrict__ Wz1, const float* __restrict__ Wz2,
    float* __restrict__ hout, float* __restrict__ hsum,
    _Float16* __restrict__ z1h, _Float16* __restrict__ z2h,
    _Float16* __restrict__ z2bh) {
    const int t  = threadIdx.x;
    const int l  = t & 63, wv = t >> 6;

    __shared__ float red[44 * 4];
    __shared__ float Ssum[44];

    if (blockIdx.x < 64) {
        // ---------------- LayerNorm path ----------------
        const int b = blockIdx.x;
        float h0 = fmaxf(hpre[b * 512 + t]       + bh[t],       0.f);
        float h1 = fmaxf(hpre[b * 512 + t + 256] + bh[t + 256], 0.f);
        float s = h0 + h1, ss = h0 * h0 + h1 * h1;
#pragma unroll
        for (int m = 1; m < 64; m <<= 1) {
            s  += __shfl_xor(s, m);
            ss += __shfl_xor(ss, m);
        }
        if (l == 0) { red[wv] = s; red[4 + wv] = ss; }
        __syncthreads();
        s  = red[0] + red[1] + red[2] + red[3];
        ss = red[4] + red[5] + red[6] + red[7];
        float mean = s * (1.0f / 512.0f);
        float var  = ss * (1.0f / 512.0f) - mean * mean;
        float rstd = rsqrtf(var + EPS);
        float v0 = (h0 - mean) * rstd * ls[t]       + lb[t];
        float v1 = (h1 - mean) * rstd * ls[t + 256] + lb[t + 256];
        hout[b * 512 + t]       = v0;
        hout[b * 512 + t + 256] = v1;
        float sv = v0 + v1;
#pragma unroll
        for (int m = 1; m < 64; m <<= 1) sv += __shfl_xor(sv, m);
        if (l == 0) red[8 + wv] = sv;
        __syncthreads();
        if (t == 0) hsum[b] = red[8] + red[9] + red[10] + red[11];
        return;
    }

    // ---------------- prep path: one block per row r ----------------
    const int r  = blockIdx.x - 64;
    const int br = r >> 4, a = r & 15;

    const float* __restrict__ x1  = xz1 + br * 4096;
    const float* __restrict__ x2  = xz2 + br * 4096;
    const float* __restrict__ w1r = Wz1 + (512 + a) * 4096;
    const float* __restrict__ w2r = Wz2 + (512 + a) * 4096;

    float pm[8], pg[36];
#pragma unroll
    for (int i = 0; i < 8; ++i) pm[i] = 0.f;
#pragma unroll
    for (int i = 0; i < 36; ++i) pg[i] = 0.f;

    half8 h2keep[2];
#pragma unroll
    for (int p = 0; p < 2; ++p) {
        const int d = t + p * 256;
        half8 h1, h2;
#pragma unroll
        for (int h = 0; h < 8; ++h) {
            float z1v = x1[h * 512 + d] + w1r[h * 512 + d];
            float z2v = x2[h * 512 + d] + w2r[h * 512 + d];
            h1[h] = (_Float16)z1v;
            h2[h] = (_Float16)z2v;
        }
        *(half8*)(z1h + ((size_t)r * 512 + d) * 8) = h1;
        h2keep[p] = h2;
        float zr[8];
#pragma unroll
        for (int h = 0; h < 8; ++h) zr[h] = (float)h1[h];
#pragma unroll
        for (int h = 0; h < 8; ++h) pm[h] += zr[h];
        int id = 0;
#pragma unroll
        for (int h = 0; h < 8; ++h)
#pragma unroll
            for (int h2_ = h; h2_ < 8; ++h2_) { pg[id] += zr[h] * zr[h2_]; ++id; }
    }

#pragma unroll
    for (int m = 1; m < 64; m <<= 1) {
#pragma unroll
        for (int i = 0; i < 8; ++i)  pm[i] += __shfl_xor(pm[i], m);
#pragma unroll
        for (int i = 0; i < 36; ++i) pg[i] += __shfl_xor(pg[i], m);
    }
    if (l == 0) {
#pragma unroll
        for (int i = 0; i < 8; ++i)  red[i * 4 + wv]       = pm[i];
#pragma unroll
        for (int i = 0; i < 36; ++i) red[(8 + i) * 4 + wv] = pg[i];
    }
    __syncthreads();
    if (t < 44) Ssum[t] = red[t * 4 + 0] + red[t * 4 + 1] + red[t * 4 + 2] + red[t * 4 + 3];
    __syncthreads();

    const float C2LE = 2.8853900817779268f;  // 2*log2(e)
#pragma unroll
    for (int p = 0; p < 2; ++p) {
        const int g = t + p * 256;
        float zv[8];
#pragma unroll
        for (int h = 0; h < 8; ++h) zv[h] = (float)h2keep[p][h];
        float mean = 0.f;
#pragma unroll
        for (int h = 0; h < 8; ++h) mean = fmaf(zv[h], Ssum[h], mean);
        mean *= (1.0f / 512.0f);
        float e2 = 0.f;
        int id = 0;
#pragma unroll
        for (int h = 0; h < 8; ++h)
#pragma unroll
            for (int h2_ = h; h2_ < 8; ++h2_) {
                float p2 = zv[h] * zv[h2_] * Ssum[8 + id];
                e2 += (h2_ == h) ? p2 : 2.0f * p2;
                ++id;
            }
        e2 *= (1.0f / 512.0f);
        float var  = e2 - mean * mean;
        float sd   = sqrtf(fmaxf(var, 0.f));
        float rstd = 1.0f / (sd + EPS);
        float A = rstd * C2LE;
        z2bh[r * 512 + g] = (_Float16)(-mean * rstd * C2LE);
        half8 hs;
#pragma unroll
        for (int h = 0; h < 8; ++h) hs[h] = (_Float16)(zv[h] * A);
        *(half8*)(z2h + ((size_t)r * 512 + g) * 8) = hs;
    }
}

// ---------------- Kernel 3: MFMA bilinear + tanh + dot ----------------------
// 2048 blocks: blockIdx.x = r*2 + gh. Bias folded into MFMA K-pad slot (k=8):
// z1t pad row = {1,0,...}, hi-half A-fragment = {Bg[g],0,...}.
__global__ __launch_bounds__(256, 8) void k_main(
    const _Float16* __restrict__ z1h, const _Float16* __restrict__ z2h,
    const _Float16* __restrict__ z2bh, const float* __restrict__ hbuf,
    const float* __restrict__ hsum, float* __restrict__ yout,
    float* __restrict__ qout) {
    const int bx = blockIdx.x;
    const int r  = bx >> 1, gh = bx & 1;
    const int br = r >> 4;
    const int t  = threadIdx.x;
    const int l  = t & 63, wv = t >> 6;
    const int hi = l >> 5, l31 = l & 31;

    __shared__ __align__(16) _Float16 z1t[513 * 8];  // [d][h]; row 512 = {1,0..}
    __shared__ float ys[256];
    __shared__ float wq[4];

    // ---- stage z1 only ----
#pragma unroll
    for (int p = 0; p < 2; ++p) {
        const int d = t + p * 256;
        *(half8*)(z1t + d * 8) = *(const half8*)(z1h + ((size_t)r * 512 + d) * 8);
    }
    if (t == 0) {
        half8 one = {};
        one[0] = (_Float16)1.0f;
        *(half8*)(z1t + 512 * 8) = one;
    }
    __syncthreads();

    const float Vsum = hsum[br];
    const float* __restrict__ vrow = hbuf + br * 512;

    const f32x16 CZ = {0.f, 0.f, 0.f, 0.f, 0.f, 0.f, 0.f, 0.f,
                       0.f, 0.f, 0.f, 0.f, 0.f, 0.f, 0.f, 0.f};
    float qacc = 0.f;
#pragma unroll 1
    for (int mi = 0; mi < 2; ++mi) {
        const int m0 = (wv * 2 + mi) * 32;              // local g tile base
        half8 Af;
        if (hi) {
            half8 tmp = {};
            tmp[0] = z2bh[(size_t)r * 512 + gh * 256 + m0 + l31];
            Af = tmp;
        } else {
            Af = *(const half8*)(z2h + ((size_t)r * 512 + gh * 256 + m0 + l31) * 8);
        }
        float yac[16];
#pragma unroll
        for (int i = 0; i < 16; ++i) yac[i] = 0.f;

#pragma unroll 1
        for (int nt = 0; nt < 16; ++nt) {
            const int n0 = nt * 32;
            const int brow = hi ? 512 : (n0 + l31);
            const half8 Bf = *(const half8*)(z1t + brow * 8);
            const float vv = vrow[n0 + l31];
            f32x16 D = __builtin_amdgcn_mfma_f32_32x32x16_f16(Af, Bf, CZ, 0, 0, 0);
#pragma unroll
            for (int i = 0; i < 16; ++i) {
                float e  = __builtin_amdgcn_exp2f(D[i]);     // e^{2x}
                float r1 = __builtin_amdgcn_rcpf(e + 1.0f);
                yac[i] = fmaf(vv, r1, yac[i]);               // sum v/(e^{2x}+1)
            }
        }
#pragma unroll
        for (int i = 0; i < 16; ++i) {
#pragma unroll
            for (int m = 1; m <= 16; m <<= 1) yac[i] += __shfl_xor(yac[i], m);
        }
        if (l31 == 0) {
#pragma unroll
            for (int i = 0; i < 16; ++i) {
                const int g = m0 + (i & 3) + 8 * (i >> 2) + 4 * hi;
                float yv = fmaf(-2.0f, yac[i], Vsum);        // Vsum - 2*sum
                ys[g] = yv;
                qacc = fmaf(yv, yv, qacc);
            }
        }
    }
    qacc += __shfl_xor(qacc, 32);
    if (l == 0) wq[wv] = qacc;
    __syncthreads();
    if (t == 0) atomicAdd(qout + r, (wq[0] + wq[1] + wq[2] + wq[3]) * (1.0f / 512.0f));
    yout[r * 512 + gh * 256 + t] = ys[t];
}

// ---------------------------------------------------------------------------
extern "C" void kernel_launch(void* const* d_in, const int* in_sizes, int n_in,
                              void* d_out, int out_size, void* d_ws, size_t ws_size,
                              hipStream_t stream) {
    const float* x   = (const float*)d_in[0];   // (64, 512)
    const float* Wh  = (const float*)d_in[1];   // (512, 512)
    const float* bh  = (const float*)d_in[2];   // (512,)
    const float* ls  = (const float*)d_in[3];   // (512,)
    const float* lb  = (const float*)d_in[4];   // (512,)
    const float* Wz1 = (const float*)d_in[5];   // (528, 4096)
    const float* Wz2 = (const float*)d_in[6];   // (528, 4096)

    float* out  = (float*)d_out;
    float* hout = out;                 // 64*512
    float* qout = out + 32768;         // 64*16
    float* yout = out + 33792;         // 1024*512

    // workspace layout (bytes); xz1|xz2|hpre contiguous for one memset
    char* ws = (char*)d_ws;
    float*     xz1  = (float*)(ws);                           // 1 MB
    float*     xz2  = (float*)(ws + (1u << 20));              // 1 MB
    float*     hpre = (float*)(ws + (2u << 20));              // 128 KB
    float*     hsum = (float*)(ws + (2u << 20) + 131072);     // 256 B
    _Float16*  xh   = (_Float16*)(ws + (2u << 20) + 135168);  // 64 KB
    _Float16*  z2bh = (_Float16*)(ws + (2u << 20) + 200704);  // 1 MB
    _Float16*  z1h  = (_Float16*)(ws + (4u << 20));           // 8.4 MB
    _Float16*  z2h  = z1h + (size_t)1024 * 512 * 8;           // 8.4 MB

    hipMemsetAsync(ws, 0, (2u << 20) + 131072, stream);   // xz1, xz2, hpre
    hipMemsetAsync(qout, 0, 64 * 16 * sizeof(float), stream);

    k_xh  <<<16, 256, 0, stream>>>(x, xh);
    k_gemm<<<dim3(68, 2), 256, 0, stream>>>(xh, Wh, Wz1, Wz2, hpre, xz1, xz2);
    k_mid <<<1088, 256, 0, stream>>>(hpre, bh, ls, lb, xz1, xz2, Wz1, Wz2,
                                     hout, hsum, z1h, z2h, z2bh);
    k_main<<<2048, 256, 0, stream>>>(z1h, z2h, z2bh, hout, hsum, yout, qout);
}